// Round 6
// baseline (102.045 us; speedup 1.0000x reference)
//
#include <hip/hip_runtime.h>
#include <hip/hip_bf16.h>

// Problem constants (fixed by setup_inputs)
constexpr int BATCH = 2;
constexpr int CIN   = 16;
constexpr int COUT  = 32;
constexpr int HWD   = 32768;        // 32^3
constexpr int OFFC  = 81;           // 3*27 offset channels
constexpr int BIG   = 96;           // 3*32
constexpr int BIG2  = BIG * BIG;    // 9216
constexpr int BIGN  = BIG * BIG * BIG;  // 884736
constexpr int OUTD  = 48;
constexpr int OUT2  = OUTD * OUTD;      // 2304
constexpr int OUTN  = OUTD * OUTD * OUTD; // 110592
constexpr int NOUT  = BATCH * COUT * OUTN; // 7077888
constexpr int NBLK3 = 1728;         // fused grid: 2 bt x 24 ut x 6 vt x 6 wt

typedef __attribute__((ext_vector_type(8)))  short bf16x8;
typedef __attribute__((ext_vector_type(16))) float f32x16;

__device__ __forceinline__ float bf_lo(uint u) { return __uint_as_float(u << 16); }
__device__ __forceinline__ float bf_hi(uint u) { return __uint_as_float(u & 0xFFFF0000u); }

// ---------------------------------------------------------------------------
// K0a: weight transposes (both bf16, MFMA A-operand layout).
//  wTb [(tap*32+co)*16+ci] = bf16(conv_w[co][ci][tap])
//  pwTb[(tap*96+oc)*16+ci] = bf16(p_w[oc][ci][tap]), oc padded 81->96 w/ zeros
__global__ __launch_bounds__(256) void k_wtrans(const float* __restrict__ cw,
                                                const float* __restrict__ pw,
                                                ushort* __restrict__ wTb,
                                                ushort* __restrict__ pwTb) {
    int t = blockIdx.x * 256 + threadIdx.x;
    if (t < 13824) {
        int ci = t & 15; int rr = t >> 4; int co = rr & 31; int tap = rr >> 5;
        float v = cw[co * 432 + ci * 27 + tap];
        __hip_bfloat16 h = __float2bfloat16(v);
        wTb[t] = *(ushort*)&h;
    } else if (t < 13824 + 41472) {
        int u = t - 13824;
        int ci = u & 15; int rr = u >> 4; int oc = rr % 96; int tap = rr / 96;
        float v = (oc < 81) ? pw[oc * 432 + ci * 27 + tap] : 0.f;
        __hip_bfloat16 h = __float2bfloat16(v);
        pwTb[u] = *(ushort*)&h;
    }
}

// ---------------------------------------------------------------------------
// K0b: transpose x (b,ci,pos) -> xb bf16 channel-last (b,pos,16ci)
__global__ __launch_bounds__(256) void k_xt(const float* __restrict__ x,
                                            ushort* __restrict__ xb) {
    int t = blockIdx.x * 256 + threadIdx.x;   // 65536 threads
    int bt = t >> 15, pos = t & 32767;
    float v[16];
#pragma unroll
    for (int ci = 0; ci < 16; ci++) v[ci] = x[(bt * 16 + ci) * HWD + pos];
    uint uw[8];
#pragma unroll
    for (int cc = 0; cc < 8; cc++) {
        __hip_bfloat16 h0 = __float2bfloat16(v[2 * cc]);
        __hip_bfloat16 h1 = __float2bfloat16(v[2 * cc + 1]);
        uw[cc] = (uint)(*(ushort*)&h0) | ((uint)(*(ushort*)&h1) << 16);
    }
    uint4* xd = (uint4*)(xb + (size_t)t * 16);
    xd[0] = make_uint4(uw[0], uw[1], uw[2], uw[3]);
    xd[1] = make_uint4(uw[4], uw[5], uw[6], uw[7]);
}

// ---------------------------------------------------------------------------
// K1: offset conv (stride 1, pad 1) as implicit-GEMM MFMA.
// Block = 2x8x8 positions, 4 waves; wave = 32-pos x 32-oc MFMA tile.
// Output: POINT-MAJOR packed bf16  offP[bt][pos][n][{x,y,z,pad}]  (8 B per n)
__global__ __launch_bounds__(256) void k_offset_mfma(const ushort* __restrict__ xb,
                                                     const ushort* __restrict__ pwTb,
                                                     const float* __restrict__ p_b,
                                                     ushort* __restrict__ offP) {
    __shared__ uint4 lds[4 * 10 * 11 * 2];   // 14,080 B
    int blk = blockIdx.x;
    int bt = blk >> 8; int r = blk & 255;
    int ut = r >> 4; int vt = (r >> 2) & 3; int wt = r & 3;
    int a0 = ut * 2, b0 = vt * 8, c0 = wt * 8;
    int tid = threadIdx.x;
    int wv = tid >> 6, l = tid & 63, col = l & 31, half = l >> 5;

    const ushort* xbb = xb + (size_t)bt * HWD * 16;
    for (int s = tid; s < 800; s += 256) {
        int h = s & 1, p = s >> 1;
        int su = p / 100; int rm = p - su * 100;
        int sv = rm / 10; int sw = rm - sv * 10;
        int ga = a0 - 1 + su, gb = b0 - 1 + sv, gc = c0 - 1 + sw;
        uint4 v = make_uint4(0, 0, 0, 0);
        if ((unsigned)ga < 32u && (unsigned)gb < 32u && (unsigned)gc < 32u)
            v = *(const uint4*)(xbb + (size_t)(ga * 1024 + gb * 32 + gc) * 16 + h * 8);
        lds[((su * 10 + sv) * 11 + sw) * 2 + h] = v;
    }
    __syncthreads();

    int U = wv >> 1, V = ((wv & 1) << 2) + (col >> 3), W = col & 7;
    const uint4* wt4 = (const uint4*)pwTb;
    int a = a0 + U, b = b0 + V, c = c0 + W;
    int pos = a * 1024 + b * 32 + c;
    ushort* op = offP + ((size_t)bt * HWD + pos) * 108;   // 27 n * 4 ushorts

#pragma unroll 1
    for (int g = 0; g < 3; g++) {
        bf16x8 wf[27];
#pragma unroll
        for (int t = 0; t < 27; t++)
            wf[t] = __builtin_bit_cast(bf16x8, wt4[(t * 96 + g * 32 + col) * 2 + half]);
        f32x16 acc;
#pragma unroll
        for (int i = 0; i < 16; i++) acc[i] = 0.f;
#pragma unroll
        for (int k1 = 0; k1 < 3; k1++)
#pragma unroll
        for (int k2 = 0; k2 < 3; k2++)
#pragma unroll
        for (int k3 = 0; k3 < 3; k3++) {
            bf16x8 xf = __builtin_bit_cast(bf16x8,
                lds[(((U + k1) * 10 + (V + k2)) * 11 + (W + k3)) * 2 + half]);
            acc = __builtin_amdgcn_mfma_f32_32x32x16_bf16(wf[(k1 * 3 + k2) * 3 + k3],
                                                          xf, acc, 0, 0, 0);
        }
#pragma unroll
        for (int rg = 0; rg < 16; rg++) {
            int co = g * 32 + (rg & 3) + 8 * (rg >> 2) + 4 * half;
            if (co < 81) {
                int n = co % 27, d = co / 27;
                __hip_bfloat16 h = __float2bfloat16(acc[rg] + p_b[co]);
                op[n * 4 + d] = *(ushort*)&h;
            }
        }
    }
}

// ---------------------------------------------------------------------------
// K2+K3 fused: deformable sampling computed DIRECTLY into the conv's LDS halo
// (x_off never materialized), then conv3d(.,stride=2,pad=1) as MFMA GEMM.
// Block = 2x8x8 output tile, 4 waves; wave = 32-pos x 32-co MFMA tile.
// LDS halo: [su 0..4][sv 0..16][W even/odd slots, pitch 19][16 ci] bf16.
// Grid 1728 = 8 XCD x 216: bijective swizzle gives each XCD a contiguous slab.
__global__ __launch_bounds__(256, 3) void k_fused(const ushort* __restrict__ xb,
                                                  const ushort* __restrict__ offP,
                                                  const ushort* __restrict__ wTb,
                                                  ushort* __restrict__ o16,
                                                  float* __restrict__ psum,
                                                  float* __restrict__ psq) {
    __shared__ uint4 lds[5 * 17 * 19 * 2];   // 51,680 B
    __shared__ float ls[4][32], lq[4][32];

    // XCD-aware bijective swizzle (nwg=1728, 8 XCDs, q=216, r=0)
    int blk = (blockIdx.x & 7) * 216 + (blockIdx.x >> 3);

    int bt = blk / 864; int r = blk - bt * 864;
    int ut = r / 36; r -= ut * 36;
    int vt = r / 6;  int wt = r - vt * 6;

    int tid = threadIdx.x;
    int wv = tid >> 6, l = tid & 63;
    int col = l & 31, half = l >> 5;

    // ---- staging phase: interpolate halo points straight into LDS ----
    const ushort* xbb  = xb + (size_t)bt * HWD * 16;
    const ushort* offb = offP + (size_t)bt * HWD * 108;
    int gU0 = ut * 4 - 1, gV0 = vt * 16 - 1, gW0 = wt * 16 - 1;

    for (int s = tid; s < 1445; s += 256) {
        int su = s / 289; int rm = s - su * 289;
        int sv = rm / 17; int sw = rm - sv * 17;
        int gU = gU0 + su, gV = gV0 + sv, gW = gW0 + sw;
        uint4 r0 = make_uint4(0, 0, 0, 0), r1 = r0;
        if ((unsigned)gU < 96u && (unsigned)gV < 96u && (unsigned)gW < 96u) {
            int a = gU / 3, i = gU - a * 3;
            int b = gV / 3, j = gV - b * 3;
            int c = gW / 3, kk = gW - c * 3;
            int n = i * 9 + j * 3 + kk;
            int pos = a * 1024 + b * 32 + c;
            uint2 ou = *(const uint2*)(offb + (size_t)pos * 108 + n * 4);
            float ox = bf_lo(ou.x);
            float oy = bf_hi(ou.x);
            float oz = bf_lo(ou.y);

            // reference quirk: px is based on the SECOND coord (b)+j, py on (a)+i
            float px = (float)(b + j) + ox;
            float py = (float)(a + i) + oy;
            float pz = (float)(c + kk) + oz;

            float fx = floorf(px), fy = floorf(py), fz = floorf(pz);
            float ltx = fminf(fmaxf(fx, 0.f), 31.f);
            float lty = fminf(fmaxf(fy, 0.f), 31.f);
            float ltz = fminf(fmaxf(fz, 0.f), 31.f);
            float rbx = fminf(fmaxf(fx + 1.f, 0.f), 31.f);
            float rby = fminf(fmaxf(fy + 1.f, 0.f), 31.f);
            float rbz = fminf(fmaxf(fz + 1.f, 0.f), 31.f);
            float pcx = fminf(fmaxf(px, 0.f), 31.f);
            float pcy = fminf(fmaxf(py, 0.f), 31.f);
            float pcz = fminf(fmaxf(pz, 0.f), 31.f);

            float axl = 1.f + (ltx - pcx), axr = 1.f - (rbx - pcx);
            float ayl = 1.f + (lty - pcy), ayr = 1.f - (rby - pcy);
            float azl = 1.f + (ltz - pcz), azr = 1.f - (rbz - pcz);

            float g_lt = axl * ayl * azl;
            float g_rb = axr * ayr * azr;
            float g_lb = axl * ayr * azl;
            float g_rt = axr * ayl * azl;
            float g_lf = axl * ayl * azr;
            float g_rf = axr * ayr * azl;

            int iltx = (int)ltx, ilty = (int)lty, iltz = (int)ltz;
            int irbx = (int)rbx, irby = (int)rby, irbz = (int)rbz;

            int i_lt = iltx * 1024 + ilty * 32 + iltz;
            int i_rb = irbx * 1024 + irby * 32 + irbz;
            int i_lb = iltx * 1024 + irby * 32 + iltz;
            int i_rt = irbx * 1024 + ilty * 32 + iltz;
            int i_lf = iltx * 1024 + ilty * 32 + irbz;
            int i_rf = irbx * 1024 + irby * 32 + iltz;

            float acc[16];
#pragma unroll
            for (int q = 0; q < 16; q++) acc[q] = 0.f;

            auto corner = [&](float g, int ip) {
                const uint4* p = (const uint4*)(xbb + (size_t)ip * 16);
                uint4 u0 = p[0], u1 = p[1];
                acc[0]  += g * bf_lo(u0.x); acc[1]  += g * bf_hi(u0.x);
                acc[2]  += g * bf_lo(u0.y); acc[3]  += g * bf_hi(u0.y);
                acc[4]  += g * bf_lo(u0.z); acc[5]  += g * bf_hi(u0.z);
                acc[6]  += g * bf_lo(u0.w); acc[7]  += g * bf_hi(u0.w);
                acc[8]  += g * bf_lo(u1.x); acc[9]  += g * bf_hi(u1.x);
                acc[10] += g * bf_lo(u1.y); acc[11] += g * bf_hi(u1.y);
                acc[12] += g * bf_lo(u1.z); acc[13] += g * bf_hi(u1.z);
                acc[14] += g * bf_lo(u1.w); acc[15] += g * bf_hi(u1.w);
            };
            corner(g_lt, i_lt);
            corner(g_rb, i_rb);
            corner(g_lb, i_lb);
            corner(g_rt, i_rt);
            corner(g_lf, i_lf);
            corner(g_rf, i_rf);

            uint uw[8];
#pragma unroll
            for (int cc = 0; cc < 8; cc++) {
                __hip_bfloat16 h0 = __float2bfloat16(acc[2 * cc]);
                __hip_bfloat16 h1 = __float2bfloat16(acc[2 * cc + 1]);
                uw[cc] = (uint)(*(ushort*)&h0) | ((uint)(*(ushort*)&h1) << 16);
            }
            r0 = make_uint4(uw[0], uw[1], uw[2], uw[3]);
            r1 = make_uint4(uw[4], uw[5], uw[6], uw[7]);
        }
        int slot = (sw & 1) * 9 + (sw >> 1);   // even/odd W split
        lds[((su * 17 + sv) * 19 + slot) * 2 + 0] = r0;
        lds[((su * 17 + sv) * 19 + slot) * 2 + 1] = r1;
    }

    // preload 27 weight fragments (A operand): w[co=col][ci=half*8..+7]
    bf16x8 wf[27];
    const uint4* wt4 = (const uint4*)wTb;
#pragma unroll
    for (int t = 0; t < 27; t++)
        wf[t] = __builtin_bit_cast(bf16x8, wt4[(t * 32 + col) * 2 + half]);

    __syncthreads();

    // ---- MFMA phase ----
    int U = wv >> 1, V = (wv & 1) * 4 + (col >> 3), W = col & 7;
    const uint4* lp = &lds[(((2 * U * 17 + 2 * V) * 19) + W) * 2 + half];

    f32x16 acc;
#pragma unroll
    for (int i = 0; i < 16; i++) acc[i] = 0.f;

#pragma unroll
    for (int k1 = 0; k1 < 3; k1++)
#pragma unroll
    for (int k2 = 0; k2 < 3; k2++)
#pragma unroll
    for (int k3 = 0; k3 < 3; k3++) {
        // sw = 2W + k3 -> slot offset {0, 9, 1}
        const int so = (k3 == 0) ? 0 : (k3 == 1 ? 9 : 1);
        const int off2 = ((k1 * 17 + k2) * 19 + so) * 2;
        bf16x8 xf = __builtin_bit_cast(bf16x8, lp[off2]);
        acc = __builtin_amdgcn_mfma_f32_32x32x16_bf16(wf[(k1 * 3 + k2) * 3 + k3],
                                                      xf, acc, 0, 0, 0);
    }

    // store bf16: D row = co = (rg&3)+8*(rg>>2)+4*half, col = position
    int u = ut * 2 + U, v = vt * 8 + V, wg = wt * 8 + W;
    size_t posg = (size_t)u * OUT2 + v * OUTD + wg;
    ushort* ob = o16 + (size_t)bt * COUT * OUTN;
#pragma unroll
    for (int rg = 0; rg < 16; rg++) {
        int co = (rg & 3) + 8 * (rg >> 2) + 4 * half;
        __hip_bfloat16 h = __float2bfloat16(acc[rg]);
        ob[(size_t)co * OUTN + posg] = *(ushort*)&h;
    }

    // fixed-order block stats (fp32, from exact accumulators)
#pragma unroll
    for (int rg = 0; rg < 16; rg++) {
        float s = acc[rg], q = acc[rg] * acc[rg];
#pragma unroll
        for (int o = 1; o < 32; o <<= 1) {
            s += __shfl_xor(s, o);
            q += __shfl_xor(q, o);
        }
        if (col == 0) {
            int co = (rg & 3) + 8 * (rg >> 2) + 4 * half;
            ls[wv][co] = s; lq[wv][co] = q;
        }
    }
    __syncthreads();
    if (tid < 32) {
        float s = ls[0][tid] + ls[1][tid] + ls[2][tid] + ls[3][tid];
        float q = lq[0][tid] + lq[1][tid] + lq[2][tid] + lq[3][tid];
        psum[blk * 32 + tid] = s;
        psq[blk * 32 + tid]  = q;
    }
}

// ---------------------------------------------------------------------------
// K4: reduce partials -> per-channel scale A and shift B
__global__ __launch_bounds__(256) void k_stats(const float* __restrict__ psum,
                                               const float* __restrict__ psq,
                                               const float* __restrict__ gamma,
                                               const float* __restrict__ beta,
                                               float* __restrict__ stats) {
    int co  = blockIdx.x;
    int tid = threadIdx.x;
    float s = 0.f, q = 0.f;
    for (int i = tid; i < NBLK3; i += 256) {
        s += psum[i * 32 + co];
        q += psq[i * 32 + co];
    }
    __shared__ float ss[256], sq[256];
    ss[tid] = s; sq[tid] = q;
    __syncthreads();
    for (int st = 128; st > 0; st >>= 1) {
        if (tid < st) { ss[tid] += ss[tid + st]; sq[tid] += sq[tid + st]; }
        __syncthreads();
    }
    if (tid == 0) {
        const float N = 221184.f;  // 2*48^3
        float mean = ss[0] / N;
        float var  = sq[0] / N - mean * mean;
        float inv  = rsqrtf(var + 1e-5f);
        float A = gamma[co] * inv;
        stats[co * 2]     = A;
        stats[co * 2 + 1] = beta[co] - A * mean;
    }
}

// ---------------------------------------------------------------------------
// K5: y = A*bf16(o) + B; out = y * sigmoid(y)  (8 values/thread)
__global__ __launch_bounds__(256) void k_bn_silu(const ushort* __restrict__ o16,
                                                 const float* __restrict__ stats,
                                                 float* __restrict__ out) {
    int t = blockIdx.x * 256 + threadIdx.x;       // NOUT/8 threads
    int co = (t / (OUTN / 8)) & 31;
    float A = stats[co * 2], B = stats[co * 2 + 1];
    uint4 u = ((const uint4*)o16)[t];
    float o[8] = {bf_lo(u.x), bf_hi(u.x), bf_lo(u.y), bf_hi(u.y),
                  bf_lo(u.z), bf_hi(u.z), bf_lo(u.w), bf_hi(u.w)};
    float y[8];
#pragma unroll
    for (int q = 0; q < 8; q++) {
        float yy = A * o[q] + B;
        y[q] = yy / (1.f + __expf(-yy));
    }
    float4* dst = (float4*)(out + (size_t)t * 8);
    dst[0] = make_float4(y[0], y[1], y[2], y[3]);
    dst[1] = make_float4(y[4], y[5], y[6], y[7]);
}

// ---------------------------------------------------------------------------
extern "C" void kernel_launch(void* const* d_in, const int* in_sizes, int n_in,
                              void* d_out, int out_size, void* d_ws, size_t ws_size,
                              hipStream_t stream) {
    const float* x      = (const float*)d_in[0];
    const float* p_w    = (const float*)d_in[1];
    const float* p_b    = (const float*)d_in[2];
    const float* conv_w = (const float*)d_in[3];
    const float* gamma  = (const float*)d_in[4];
    const float* beta   = (const float*)d_in[5];
    float* out = (float*)d_out;
    float* ws  = (float*)d_ws;

    float* psum  = ws;                       // 1728*32 = 55,296 f
    float* psq   = psum + 55296;             // 55,296 f
    float* stats = psq + 55296;              // 64 f
    ushort* wTb  = (ushort*)(stats + 64);    // 13,824 bf16
    ushort* pwTb = wTb + 13824;              // 41,472 bf16
    ushort* xb   = pwTb + 41472;             // 1,048,576 bf16  (16B-aligned)
    ushort* offP = xb + 1048576;             // 2*32768*108 = 7,077,888 bf16
    ushort* o16  = offP + 7077888;           // 7,077,888 bf16  (16B-aligned)

    k_wtrans<<<216, 256, 0, stream>>>(conv_w, p_w, wTb, pwTb);
    k_xt<<<256, 256, 0, stream>>>(x, xb);
    k_offset_mfma<<<512, 256, 0, stream>>>(xb, pwTb, p_b, offP);
    k_fused<<<NBLK3, 256, 0, stream>>>(xb, offP, wTb, o16, psum, psq);
    k_stats<<<32, 256, 0, stream>>>(psum, psq, gamma, beta, stats);
    k_bn_silu<<<NOUT / 2048, 256, 0, stream>>>(o16, stats, out);
}